// Round 6
// baseline (3431.659 us; speedup 1.0000x reference)
//
#include <hip/hip_runtime.h>
#include <hip/hip_cooperative_groups.h>
#include <math.h>

namespace cg = cooperative_groups;

#define Bv 128
#define Pv 196
#define Ev 512
#define Hv 512
#define Vv 12000
#define Tv 20

typedef unsigned short u16;
typedef unsigned int u32;
typedef short bf16x8 __attribute__((ext_vector_type(8)));
typedef float f32x4 __attribute__((ext_vector_type(4)));

__device__ __forceinline__ float sigf(float x) { return 1.0f / (1.0f + __expf(-x)); }
__device__ __forceinline__ u16 f2bf(float f) {
    u32 x = __float_as_uint(f);
    return (u16)((x + 0x7FFFu + ((x >> 16) & 1u)) >> 16);   // RNE
}
__device__ __forceinline__ u32 pack2(float a, float b) {
    return (u32)f2bf(a) | ((u32)f2bf(b) << 16);
}
__device__ __forceinline__ float bfl(u32 u) { return __uint_as_float(u << 16); }
__device__ __forceinline__ float bfh(u32 u) { return __uint_as_float(u & 0xFFFF0000u); }
__device__ __forceinline__ float bf2f(u16 u) { return __uint_as_float(((u32)u) << 16); }

__device__ __forceinline__ void cvt_loop(const float* __restrict__ src,
                                         u16* __restrict__ dst, int n4,
                                         int g, int gs) {
    for (int i = g; i < n4; i += gs) {
        float4 v = ((const float4*)src)[i];
        uint2 o;
        o.x = pack2(v.x, v.y);
        o.y = pack2(v.z, v.w);
        ((uint2*)dst)[i] = o;
    }
}

// ---------------------------------------------------------------------------
// 128m x 64n x 512k MFMA tile, 256 threads (one sub-unit of a 512-thr block).
// __syncthreads() spans the whole block: both sub-units always execute the
// same barrier sequence (active flag only guards memory ops).
// MODE 0: att1 (bf16 out, +bias). MODE 1: beta (ghall = h*sig(acc+bias)).
// MODE 2: logits (fp32 out, n<Vv guard, m -> (t,b) unscramble).
// ---------------------------------------------------------------------------
template <int MODE>
__device__ void gemm_tile(const u16* __restrict__ A, const u16* __restrict__ B,
                          const float* __restrict__ bias, void* __restrict__ dst,
                          const u16* __restrict__ hsrc,
                          int m0, int n0, bool act,
                          u16 (*As)[72], u16 (*Bs)[72], int t256) {
    const int lane = t256 & 63, wid = t256 >> 6;
    const int wm = wid >> 1, wn = wid & 1;
    f32x4 acc[4][2] = {};
    for (int kt = 0; kt < 8; kt++) {
        if (act) {
#pragma unroll
            for (int p = 0; p < 4; p++) {
                int flat = p * 256 + t256, row = flat >> 3, ch = flat & 7;
                *(uint4*)&As[row][ch * 8] = *(const uint4*)&A[(size_t)(m0 + row) * 512 + kt * 64 + ch * 8];
            }
#pragma unroll
            for (int p = 0; p < 2; p++) {
                int flat = p * 256 + t256, row = flat >> 3, ch = flat & 7;
                if (MODE != 2 || (n0 + row) < Vv)
                    *(uint4*)&Bs[row][ch * 8] = *(const uint4*)&B[(size_t)(n0 + row) * 512 + kt * 64 + ch * 8];
            }
        }
        __syncthreads();
#pragma unroll
        for (int ks = 0; ks < 2; ks++) {
            int kk = ks * 32 + (lane >> 4) * 8;
            bf16x8 af[4], bfr[2];
#pragma unroll
            for (int mf = 0; mf < 4; mf++) af[mf] = *(const bf16x8*)&As[wm * 64 + mf * 16 + (lane & 15)][kk];
#pragma unroll
            for (int nf = 0; nf < 2; nf++) bfr[nf] = *(const bf16x8*)&Bs[wn * 32 + nf * 16 + (lane & 15)][kk];
#pragma unroll
            for (int mf = 0; mf < 4; mf++)
#pragma unroll
                for (int nf = 0; nf < 2; nf++)
                    acc[mf][nf] = __builtin_amdgcn_mfma_f32_16x16x32_bf16(af[mf], bfr[nf], acc[mf][nf], 0, 0, 0);
        }
        __syncthreads();
    }
    if (!act) return;
#pragma unroll
    for (int mf = 0; mf < 4; mf++)
#pragma unroll
        for (int nf = 0; nf < 2; nf++)
#pragma unroll
            for (int r = 0; r < 4; r++) {
                int m = m0 + wm * 64 + mf * 16 + (lane >> 4) * 4 + r;
                int n = n0 + wn * 32 + nf * 16 + (lane & 15);
                float v = acc[mf][nf][r];
                if (MODE == 0) {
                    ((u16*)dst)[(size_t)m * 512 + n] = f2bf(v + bias[n]);
                } else if (MODE == 1) {
                    float h = bf2f(hsrc[(size_t)m * 512 + n]);
                    ((u16*)dst)[(size_t)m * 512 + n] = f2bf(h * sigf(v + bias[n]));
                } else {
                    if (n < Vv) {
                        int tt = m >> 7, b = m & 127;
                        ((float*)dst)[(size_t)b * (Tv * Vv) + (size_t)tt * Vv + n] = v + bias[n];
                    }
                }
            }
}

// ---------------------------------------------------------------------------
// attn phase body: one block (512 thr) per b.  Ported verbatim from R5 k_attn.
// ---------------------------------------------------------------------------
__device__ void attn_block(const u16* __restrict__ att1b, const u16* __restrict__ encb,
                           const u16* __restrict__ hprev, const u16* __restrict__ Wdb,
                           const float* __restrict__ bd, const float* __restrict__ Wf,
                           u16* __restrict__ ctxb, float* __restrict__ alpha_out,
                           int t, int b, int tid, float* smem) {
    float* h_s = smem;            // 512
    float* att2_s = smem + 512;   // 512
    float* e_s = smem + 1024;     // 200
    float* alpha_s = smem + 1224; // 200

    h_s[tid] = bf2f(hprev[b * 512 + tid]);
    __syncthreads();

    {   // att2[tid] = dot(Wd[tid,:], h) + bd
        float acc = bd[tid];
        const uint4* wrow = (const uint4*)&Wdb[(size_t)tid * 512];
        const float4* hv4 = (const float4*)h_s;
#pragma unroll 4
        for (int i = 0; i < 64; i++) {
            uint4 w = wrow[i];
            float4 x0 = hv4[2 * i], x1 = hv4[2 * i + 1];
            acc += bfl(w.x) * x0.x + bfh(w.x) * x0.y + bfl(w.y) * x0.z + bfh(w.y) * x0.w
                 + bfl(w.z) * x1.x + bfh(w.z) * x1.y + bfl(w.w) * x1.z + bfh(w.w) * x1.w;
        }
        att2_s[tid] = acc;
    }
    __syncthreads();

    const int lane = tid & 63;
    const int wv = tid >> 6;
    float att2r[8], wfr[8];
#pragma unroll
    for (int j = 0; j < 8; j++) {
        att2r[j] = att2_s[lane * 8 + j];
        wfr[j] = Wf[lane * 8 + j];
    }
    for (int p = wv; p < 196; p += 8) {
        uint4 q = *(const uint4*)&att1b[((size_t)(b * 196 + p)) * 512 + lane * 8];
        float s = wfr[0] * fmaxf(bfl(q.x) + att2r[0], 0.f) + wfr[1] * fmaxf(bfh(q.x) + att2r[1], 0.f)
                + wfr[2] * fmaxf(bfl(q.y) + att2r[2], 0.f) + wfr[3] * fmaxf(bfh(q.y) + att2r[3], 0.f)
                + wfr[4] * fmaxf(bfl(q.z) + att2r[4], 0.f) + wfr[5] * fmaxf(bfh(q.z) + att2r[5], 0.f)
                + wfr[6] * fmaxf(bfl(q.w) + att2r[6], 0.f) + wfr[7] * fmaxf(bfh(q.w) + att2r[7], 0.f);
#pragma unroll
        for (int off = 32; off; off >>= 1) s += __shfl_xor(s, off);
        if (lane == 0) e_s[p] = s;
    }
    __syncthreads();

    if (wv == 0) {
        float v0 = e_s[lane], v1 = e_s[lane + 64], v2 = e_s[lane + 128];
        float v3 = (lane < 4) ? e_s[lane + 192] : -1e30f;
        float mx = fmaxf(fmaxf(v0, v1), fmaxf(v2, v3));
#pragma unroll
        for (int off = 32; off; off >>= 1) mx = fmaxf(mx, __shfl_xor(mx, off));
        float x0 = __expf(v0 - mx), x1 = __expf(v1 - mx), x2 = __expf(v2 - mx);
        float x3 = (lane < 4) ? __expf(v3 - mx) : 0.f;
        float sm = x0 + x1 + x2 + x3;
#pragma unroll
        for (int off = 32; off; off >>= 1) sm += __shfl_xor(sm, off);
        float inv = 1.0f / sm;
        x0 *= inv; x1 *= inv; x2 *= inv; x3 *= inv;
        alpha_s[lane] = x0; alpha_s[lane + 64] = x1; alpha_s[lane + 128] = x2;
        if (lane < 4) alpha_s[lane + 192] = x3;
        float* ao = alpha_out + ((size_t)b * Tv + t) * 196;
        ao[lane] = x0; ao[lane + 64] = x1; ao[lane + 128] = x2;
        if (lane < 4) ao[lane + 192] = x3;
    }
    __syncthreads();

    {   // ctx[tid] = sum_p alpha[p]*enc[b,p,tid]
        float acc = 0.f;
        const u16* ecol = &encb[(size_t)b * 196 * 512 + tid];
#pragma unroll 4
        for (int p = 0; p < 196; p++) acc += alpha_s[p] * bf2f(ecol[(size_t)p * 512]);
        ctxb[b * 512 + tid] = f2bf(acc);
    }
}

// ---------------------------------------------------------------------------
// gates+LSTM phase body: block bid (0..31) = jg; sub = mh.  256 thr per sub.
// Ported from R5 k_gateslstm.
// ---------------------------------------------------------------------------
__device__ void gates_block(const float* __restrict__ embt, const int* __restrict__ caps,
                            const u16* __restrict__ ctxb, const u16* __restrict__ hprev,
                            const u16* __restrict__ Wihb, const u16* __restrict__ Whhb,
                            const float* __restrict__ bih, const float* __restrict__ bhh,
                            float* __restrict__ cbuf, u16* __restrict__ hnext,
                            int t, int jg, int mh, int t256,
                            u16 (*As)[72], u16 (*Bs)[72], float (*glds)[64][16]) {
    const int lane = t256 & 63, wid = t256 >> 6;
    const int wm = wid >> 1, wn = wid & 1;
    f32x4 acc[2][2] = {};

    for (int kt = 0; kt < 24; kt++) {
#pragma unroll
        for (int p = 0; p < 2; p++) {     // A: 64 rows x 8 chunks
            int flat = p * 256 + t256, row = flat >> 3, ch = flat & 7;
            int brow = mh * 64 + row;
            uint4 v;
            if (kt < 8) {
                int cap = caps[brow * Tv + t];
                const float4* s = (const float4*)&embt[(size_t)cap * 512 + kt * 64 + ch * 8];
                float4 f0 = s[0], f1 = s[1];
                v.x = pack2(f0.x, f0.y); v.y = pack2(f0.z, f0.w);
                v.z = pack2(f1.x, f1.y); v.w = pack2(f1.z, f1.w);
            } else if (kt < 16) {
                v = *(const uint4*)&ctxb[(size_t)brow * 512 + (kt - 8) * 64 + ch * 8];
            } else {
                v = *(const uint4*)&hprev[(size_t)brow * 512 + (kt - 16) * 64 + ch * 8];
            }
            *(uint4*)&As[row][ch * 8] = v;
        }
#pragma unroll
        for (int p = 0; p < 2; p++) {     // B: 64 rows (16 j x 4 q)
            int flat = p * 256 + t256, row = flat >> 3, ch = flat & 7;
            int n = (row >> 4) * 512 + jg * 16 + (row & 15);
            uint4 v;
            if (kt < 16) v = *(const uint4*)&Wihb[(size_t)n * 1024 + kt * 64 + ch * 8];
            else         v = *(const uint4*)&Whhb[(size_t)n * 512 + (kt - 16) * 64 + ch * 8];
            *(uint4*)&Bs[row][ch * 8] = v;
        }
        __syncthreads();
#pragma unroll
        for (int ks = 0; ks < 2; ks++) {
            int kk = ks * 32 + (lane >> 4) * 8;
            bf16x8 af[2], bfr[2];
#pragma unroll
            for (int mf = 0; mf < 2; mf++) af[mf] = *(const bf16x8*)&As[wm * 32 + mf * 16 + (lane & 15)][kk];
#pragma unroll
            for (int nf = 0; nf < 2; nf++) bfr[nf] = *(const bf16x8*)&Bs[wn * 32 + nf * 16 + (lane & 15)][kk];
#pragma unroll
            for (int mf = 0; mf < 2; mf++)
#pragma unroll
                for (int nf = 0; nf < 2; nf++)
                    acc[mf][nf] = __builtin_amdgcn_mfma_f32_16x16x32_bf16(af[mf], bfr[nf], acc[mf][nf], 0, 0, 0);
        }
        __syncthreads();
    }
#pragma unroll
    for (int mf = 0; mf < 2; mf++)
#pragma unroll
        for (int nf = 0; nf < 2; nf++) {
            int q = wn * 2 + nf;
            int jj = lane & 15;
#pragma unroll
            for (int r = 0; r < 4; r++) {
                int m = wm * 32 + mf * 16 + (lane >> 4) * 4 + r;
                glds[q][m][jj] = acc[mf][nf][r];
            }
        }
    __syncthreads();
#pragma unroll
    for (int i = 0; i < 4; i++) {
        int idx = i * 256 + t256;
        int m = idx >> 4, jj = idx & 15;
        int col = jg * 16 + jj;
        int brow = mh * 64 + m;
        float gi = glds[0][m][jj] + bih[col] + bhh[col];
        float gf = glds[1][m][jj] + bih[col + 512] + bhh[col + 512];
        float gg = glds[2][m][jj] + bih[col + 1024] + bhh[col + 1024];
        float go = glds[3][m][jj] + bih[col + 1536] + bhh[col + 1536];
        float cn = sigf(gf) * cbuf[brow * 512 + col] + sigf(gi) * tanhf(gg);
        float hn = sigf(go) * tanhf(cn);
        cbuf[brow * 512 + col] = cn;
        hnext[brow * 512 + col] = f2bf(hn);
    }
}

// ---------------------------------------------------------------------------
// THE mega kernel: whole computation, one cooperative dispatch.
// 256 blocks x 512 thr (1 block/CU).  Two 256-thr GEMM sub-units per block.
// ---------------------------------------------------------------------------
__global__ __launch_bounds__(512) void k_mega(
    const float* __restrict__ enc, const int* __restrict__ caps,
    const float* __restrict__ embt,
    const float* __restrict__ We, const float* __restrict__ bea,
    const float* __restrict__ Wd, const float* __restrict__ bd,
    const float* __restrict__ Wf,
    const float* __restrict__ Wih, const float* __restrict__ bih,
    const float* __restrict__ Whh, const float* __restrict__ bhh,
    const float* __restrict__ Wb, const float* __restrict__ bb,
    const float* __restrict__ Wfc, const float* __restrict__ bfc,
    float* __restrict__ out, float* __restrict__ alpha_out,
    u16* __restrict__ encb, u16* __restrict__ att1b,
    u16* __restrict__ Wfcb, u16* __restrict__ Wihb, u16* __restrict__ Whhb,
    u16* __restrict__ Web, u16* __restrict__ Wdb, u16* __restrict__ Wbb,
    u16* __restrict__ ctxb, u16* __restrict__ hall, u16* __restrict__ ghall,
    float* __restrict__ cbuf) {
    cg::grid_group grid = cg::this_grid();
    const int bid = blockIdx.x;
    const int tid = threadIdx.x;
    const int sub = tid >> 8;
    const int t256 = tid & 255;
    const int unit = bid * 2 + sub;

    __shared__ u16 As[2][128][72];
    __shared__ u16 Bs[2][64][72];
    __shared__ float gate_lds[2][4][64][16];
    __shared__ float attn_f[1424];

    // ---- P0: bf16 conversions + zero h0/c ----
    {
        int g = bid * 512 + tid, gs = 256 * 512;
        cvt_loop(enc, encb, 12845056 / 4, g, gs);
        cvt_loop(Wfc, Wfcb, 6144000 / 4, g, gs);
        cvt_loop(Wih, Wihb, 2097152 / 4, g, gs);
        cvt_loop(Whh, Whhb, 1048576 / 4, g, gs);
        cvt_loop(We, Web, 262144 / 4, g, gs);
        cvt_loop(Wd, Wdb, 262144 / 4, g, gs);
        cvt_loop(Wb, Wbb, 262144 / 4, g, gs);
        for (int i = g; i < 32768; i += gs) ((u32*)hall)[i] = 0u;   // h_{-1}
        for (int i = g; i < 65536; i += gs) cbuf[i] = 0.f;
    }
    grid.sync();

    // ---- P1: att1 = enc @ We^T + be  (1568 tiles, 4 rounds) ----
    for (int r = 0; r < 4; r++) {
        int tile = unit + r * 512;
        bool act = tile < 1568;
        int tt = act ? tile : 0;
        gemm_tile<0>(encb, Web, bea, att1b, nullptr,
                     (tt / 8) * 128, (tt % 8) * 64, act, As[sub], Bs[sub], t256);
    }
    grid.sync();

    // ---- recurrence ----
    for (int t = 0; t < Tv; t++) {
        const u16* hprev = hall + (size_t)t * 65536;
        u16* hnext = hall + (size_t)(t + 1) * 65536;
        if (bid < 128)
            attn_block(att1b, encb, hprev, Wdb, bd, Wf, ctxb, alpha_out, t, bid, tid, attn_f);
        grid.sync();
        if (bid < 32)
            gates_block(embt, caps, ctxb, hprev, Wihb, Whhb, bih, bhh, cbuf, hnext,
                        t, bid, sub, t256, As[sub], Bs[sub], gate_lds[sub]);
        grid.sync();
    }

    // ---- beta gate (batched, 160 tiles, 1 round) ----
    {
        bool act = unit < 160;
        int tt = act ? unit : 0;
        gemm_tile<1>(hall + 65536, Wbb, bb, ghall, hall + 65536,
                     (tt / 8) * 128, (tt % 8) * 64, act, As[sub], Bs[sub], t256);
    }
    grid.sync();

    // ---- logits (batched, 3760 tiles, 8 rounds) ----
    for (int r = 0; r < 8; r++) {
        int tile = unit + r * 512;
        bool act = tile < 3760;
        int tt = act ? tile : 0;
        gemm_tile<2>(ghall, Wfcb, bfc, out, nullptr,
                     (tt / 188) * 128, (tt % 188) * 64, act, As[sub], Bs[sub], t256);
    }
}

// ===========================================================================
// Fallback path (R5 kernels, launched only if cooperative launch fails)
// ===========================================================================
__global__ __launch_bounds__(256) void k_cvt(const float* __restrict__ src,
                                             u16* __restrict__ dst, int n4) {
    for (int i = blockIdx.x * 256 + threadIdx.x; i < n4; i += gridDim.x * 256) {
        float4 v = ((const float4*)src)[i];
        uint2 o;
        o.x = pack2(v.x, v.y);
        o.y = pack2(v.z, v.w);
        ((uint2*)dst)[i] = o;
    }
}

__global__ __launch_bounds__(256) void k_att1_mfma(const u16* __restrict__ A,
                                                   const u16* __restrict__ Bw,
                                                   const float* __restrict__ bias,
                                                   u16* __restrict__ C) {
    __shared__ u16 As[128][72];
    __shared__ u16 Bs[64][72];
    gemm_tile<0>(A, Bw, bias, C, nullptr, blockIdx.y * 128, blockIdx.x * 64, true,
                 As, Bs, threadIdx.x);
}

__global__ __launch_bounds__(512) void k_attn_g(const u16* att1b, const u16* encb,
                                                const u16* hprev, const u16* Wdb,
                                                const float* bd, const float* Wf,
                                                u16* ctxb, float* alpha_out, int t) {
    __shared__ float smem[1424];
    attn_block(att1b, encb, hprev, Wdb, bd, Wf, ctxb, alpha_out, t, blockIdx.x,
               threadIdx.x, smem);
}

__global__ __launch_bounds__(256) void k_gates_g(const float* embt, const int* caps,
                                                 const u16* ctxb, const u16* hprev,
                                                 const u16* Wihb, const u16* Whhb,
                                                 const float* bih, const float* bhh,
                                                 float* cbuf, u16* hnext, int t) {
    __shared__ u16 As[64][72];
    __shared__ u16 Bs[64][72];
    __shared__ float glds[4][64][16];
    gates_block(embt, caps, ctxb, hprev, Wihb, Whhb, bih, bhh, cbuf, hnext,
                t, blockIdx.x, blockIdx.y, threadIdx.x, As, Bs, glds);
}

__global__ __launch_bounds__(256) void k_beta_g(const u16* hall1, const u16* Wbb,
                                                const float* bb, u16* ghall) {
    __shared__ u16 As[128][72];
    __shared__ u16 Bs[64][72];
    gemm_tile<1>(hall1, Wbb, bb, ghall, hall1, blockIdx.y * 128, blockIdx.x * 64, true,
                 As, Bs, threadIdx.x);
}

__global__ __launch_bounds__(256) void k_logits_g(const u16* ghall, const u16* Wfcb,
                                                  const float* bfc, float* out) {
    __shared__ u16 As[128][72];
    __shared__ u16 Bs[64][72];
    gemm_tile<2>(ghall, Wfcb, bfc, out, nullptr, blockIdx.y * 128, blockIdx.x * 64, true,
                 As, Bs, threadIdx.x);
}

// ---------------------------------------------------------------------------
extern "C" void kernel_launch(void* const* d_in, const int* in_sizes, int n_in,
                              void* d_out, int out_size, void* d_ws, size_t ws_size,
                              hipStream_t stream) {
    const float* enc = (const float*)d_in[0];
    const int* caps = (const int*)d_in[1];
    const float* embt = (const float*)d_in[2];
    const float* We = (const float*)d_in[3];
    const float* bea = (const float*)d_in[4];
    const float* Wd = (const float*)d_in[5];
    const float* bd = (const float*)d_in[6];
    const float* Wf = (const float*)d_in[7];
    // d_in[8] = bf_att: constant across p, cancels in softmax
    const float* Wih = (const float*)d_in[9];
    const float* bih = (const float*)d_in[10];
    const float* Whh = (const float*)d_in[11];
    const float* bhh = (const float*)d_in[12];
    const float* Wb = (const float*)d_in[13];
    const float* bb = (const float*)d_in[14];
    const float* Wfc = (const float*)d_in[15];
    const float* bfc = (const float*)d_in[16];

    float* out = (float*)d_out;
    float* alpha_out = out + (size_t)Bv * Tv * Vv;

    u16* encb = (u16*)d_ws;                       // 12,845,056
    u16* att1b = encb + (size_t)12845056;         // 12,845,056
    u16* Wfcb = att1b + (size_t)12845056;         // 6,144,000
    u16* Wihb = Wfcb + 6144000;                   // 2,097,152
    u16* Whhb = Wihb + 2097152;                   // 1,048,576
    u16* Web = Whhb + 1048576;                    // 262,144
    u16* Wdb = Web + 262144;                      // 262,144
    u16* Wbb = Wdb + 262144;                      // 262,144
    u16* ctxb = Wbb + 262144;                     // 65,536
    u16* hall = ctxb + 65536;                     // 21*65536
    u16* ghall = hall + 21 * 65536;               // 20*65536
    float* cbuf = (float*)(ghall + 20 * 65536);   // 65,536 f32

    void* kargs[] = {
        (void*)&enc, (void*)&caps, (void*)&embt, (void*)&We, (void*)&bea,
        (void*)&Wd, (void*)&bd, (void*)&Wf, (void*)&Wih, (void*)&bih,
        (void*)&Whh, (void*)&bhh, (void*)&Wb, (void*)&bb, (void*)&Wfc,
        (void*)&bfc, (void*)&out, (void*)&alpha_out, (void*)&encb, (void*)&att1b,
        (void*)&Wfcb, (void*)&Wihb, (void*)&Whhb, (void*)&Web, (void*)&Wdb,
        (void*)&Wbb, (void*)&ctxb, (void*)&hall, (void*)&ghall, (void*)&cbuf};

    hipError_t err = hipLaunchCooperativeKernel((void*)k_mega, dim3(256), dim3(512),
                                                kargs, 0, stream);
    if (err == hipSuccess) return;

    // -------- fallback: R5 multi-launch path --------
    hipMemsetAsync(hall, 0, 65536 * sizeof(u16), stream);
    hipMemsetAsync(cbuf, 0, 65536 * sizeof(float), stream);
    k_cvt<<<1024, 256, 0, stream>>>(enc, encb, 12845056 / 4);
    k_cvt<<<1024, 256, 0, stream>>>(Wfc, Wfcb, 6144000 / 4);
    k_cvt<<<512, 256, 0, stream>>>(Wih, Wihb, 2097152 / 4);
    k_cvt<<<256, 256, 0, stream>>>(Whh, Whhb, 1048576 / 4);
    k_cvt<<<64, 256, 0, stream>>>(We, Web, 262144 / 4);
    k_cvt<<<64, 256, 0, stream>>>(Wd, Wdb, 262144 / 4);
    k_cvt<<<64, 256, 0, stream>>>(Wb, Wbb, 262144 / 4);
    dim3 g0(8, 196);
    k_att1_mfma<<<g0, 256, 0, stream>>>(encb, Web, bea, att1b);
    for (int t = 0; t < Tv; t++) {
        const u16* hprev = hall + (size_t)t * 65536;
        u16* hnext = hall + (size_t)(t + 1) * 65536;
        k_attn_g<<<128, 512, 0, stream>>>(att1b, encb, hprev, Wdb, bd, Wf, ctxb, alpha_out, t);
        dim3 gg(32, 2);
        k_gates_g<<<gg, 256, 0, stream>>>(embt, caps, ctxb, hprev, Wihb, Whhb,
                                          bih, bhh, cbuf, hnext, t);
    }
    dim3 gb(8, 20);
    k_beta_g<<<gb, 256, 0, stream>>>(hall + 65536, Wbb, bb, ghall);
    dim3 gl(188, 20);
    k_logits_g<<<gl, 256, 0, stream>>>(ghall, Wfcb, bfc, out);
}